// Round 2
// baseline (517.014 us; speedup 1.0000x reference)
//
#include <hip/hip_runtime.h>

#define TPB 512

// Padded LDS addressing (float2 units): physical = p + 2*(p>>5).
// +2 float2 per 32 keeps 16B alignment for b128 (even p stays even), and all
// radix-4 stage strides (2048,512,128,32,8,2) land at <=4 lanes/bank-pair.
// For all stage offsets used below, (base0%32 + off%32) < 32, so
// physical(base0+off) == PX(base0) + PX(off): offsets are compile-time
// immediates in the ds instructions.
__device__ constexpr int PX(int p) { return p + 2 * (p >> 5); }

// One radix-4 stage, compile-time S. Fwd = DIF (natural->digit-reversed),
// Inv = DIT (digit-reversed->natural), conj twiddles, unscaled (growth folded
// into Hhat). For S<=512, np = tid&(S-1) is the same for all 4 butterflies
// -> one sincos per stage. For S=2048, twiddle advances by exp(-/+ i*pi/8).
template<int S, bool INV>
__device__ __forceinline__ void fft_stage(float2* __restrict__ A, int tid) {
  constexpr int LG = (S==2048)?11:(S==512)?9:(S==128)?7:(S==32)?5:(S==8)?3:1;
  constexpr int MOFF = (S==2048) ? 512 : 2048;   // butterfly-index step per m
  const int np = tid & (S - 1);
  const int base0 = ((tid >> LG) << (LG + 2)) | np;
  float2* P = A + PX(base0);
  const float tws = (INV ? 1.5707963267948966f : -1.5707963267948966f) / (float)S;
  float c1, s1;
  __sincosf(tws * (float)np, &s1, &c1);
  float c2 = c1*c1 - s1*s1, s2 = 2.f*c1*s1;
  float c3 = c1*c2 - s1*s2, s3 = c1*s2 + s1*c2;
  __syncthreads();
#pragma unroll
  for (int m = 0; m < 4; ++m) {
    if (S == 2048 && m) {   // advance twiddle: w *= exp(-/+ i*pi/8)
      constexpr float WC = 0.92387953251128674f;
      const float WS = INV ? 0.38268343236508978f : -0.38268343236508978f;
      float t = c1*WC - s1*WS; s1 = c1*WS + s1*WC; c1 = t;
      c2 = c1*c1 - s1*s1; s2 = 2.f*c1*s1;
      c3 = c1*c2 - s1*s2; s3 = c1*s2 + s1*c2;
    }
    const int o0 = PX(MOFF*m);
    const int o1 = PX(MOFF*m + S);
    const int o2 = PX(MOFF*m + 2*S);
    const int o3 = PX(MOFF*m + 3*S);
    if (!INV) {
      float2 a = P[o0], b = P[o1], c = P[o2], d = P[o3];
      float t0r = a.x + c.x, t0i = a.y + c.y;
      float t1r = a.x - c.x, t1i = a.y - c.y;
      float t2r = b.x + d.x, t2i = b.y + d.y;
      float t3r = b.x - d.x, t3i = b.y - d.y;
      float u0r = t0r + t2r, u0i = t0i + t2i;
      float u2r = t0r - t2r, u2i = t0i - t2i;
      float u1r = t1r + t3i, u1i = t1i - t3r;   // (a-c) - i(b-d)
      float u3r = t1r - t3i, u3i = t1i + t3r;   // (a-c) + i(b-d)
      P[o0] = make_float2(u0r, u0i);
      P[o1] = make_float2(u1r*c1 - u1i*s1, u1r*s1 + u1i*c1);
      P[o2] = make_float2(u2r*c2 - u2i*s2, u2r*s2 + u2i*c2);
      P[o3] = make_float2(u3r*c3 - u3i*s3, u3r*s3 + u3i*c3);
    } else {
      float2 v0 = P[o0], u1 = P[o1], u2 = P[o2], u3 = P[o3];
      float v1r = u1.x*c1 - u1.y*s1, v1i = u1.x*s1 + u1.y*c1;
      float v2r = u2.x*c2 - u2.y*s2, v2i = u2.x*s2 + u2.y*c2;
      float v3r = u3.x*c3 - u3.y*s3, v3i = u3.x*s3 + u3.y*c3;
      P[o0] = make_float2(v0.x + v1r + v2r + v3r, v0.y + v1i + v2i + v3i);
      P[o1] = make_float2(v0.x - v1i - v2r + v3i, v0.y + v1r - v2i - v3r);
      P[o2] = make_float2(v0.x - v1r + v2r - v3r, v0.y - v1i + v2i - v3i);
      P[o3] = make_float2(v0.x + v1i - v2r - v3i, v0.y - v1r - v2i + v3r);
    }
  }
}

__device__ __forceinline__ void fft_fwd(float2* A, int tid) {
  fft_stage<2048,false>(A,tid); fft_stage<512,false>(A,tid);
  fft_stage<128,false>(A,tid);  fft_stage<32,false>(A,tid);
  fft_stage<8,false>(A,tid);    fft_stage<2,false>(A,tid);
}
__device__ __forceinline__ void fft_inv(float2* A, int tid) {
  fft_stage<2,true>(A,tid);   fft_stage<8,true>(A,tid);
  fft_stage<32,true>(A,tid);  fft_stage<128,true>(A,tid);
  fft_stage<512,true>(A,tid); fft_stage<2048,true>(A,tid);
}

#define LDS_F2 8704   // PX(8191)=8701 -> 8704 float2 = 69,632 B (2 blocks/CU)

// Hhat[2f+half][p] = DIF-scrambled FFT8192(h[f, half*4096:+4096] zero-pad)/8192
__global__ __launch_bounds__(TPB, 4) void h_fft(const float* __restrict__ h,
                                                float2* __restrict__ Hbuf) {
  __shared__ __align__(16) float2 A[LDS_F2];
  const int tid = threadIdx.x;
  const int q = blockIdx.x;                     // q = 2*f + half
  const float4* h4 = (const float4*)(h + (size_t)(q >> 1) * 8192 + (size_t)(q & 1) * 4096);
#pragma unroll
  for (int m = 0; m < 2; ++m) {
    int g = tid + TPB * m;                      // 0..1023
    float4 a = h4[g];
    int p = 4 * g;
    *(float4*)&A[PX(p)]     = make_float4(a.x, 0.f, a.y, 0.f);
    *(float4*)&A[PX(p + 2)] = make_float4(a.z, 0.f, a.w, 0.f);
    int z = p + 4096;
    *(float4*)&A[PX(z)]     = make_float4(0.f, 0.f, 0.f, 0.f);
    *(float4*)&A[PX(z + 2)] = make_float4(0.f, 0.f, 0.f, 0.f);
  }
  fft_fwd(A, tid);
  __syncthreads();
  float2* orow = Hbuf + (size_t)q * 8192;
  const float sc = 1.f / 8192.f;
#pragma unroll
  for (int m = 0; m < 8; ++m) {
    int p = 2 * (tid + TPB * m);
    float4 za = *(const float4*)&A[PX(p)];      // final radix-2 in regs
    *(float4*)&orow[p] = make_float4((za.x + za.z) * sc, (za.y + za.w) * sc,
                                     (za.x - za.z) * sc, (za.y - za.w) * sc);
  }
}

// u (8,8192,256) -> xT (2048,8192). float4 both sides via XOR-swizzled tile:
// T[row][col] at physical col^(row&15); scatter phase writes 4 scalars/lane
// (2 lanes/bank), gather phase reads one float4/lane (full row = 32 banks).
__global__ void transpose_in(const float* __restrict__ u, float* __restrict__ xT) {
  __shared__ float4 T[64 * 16];
  const int l0 = blockIdx.x * 64, d0 = blockIdx.y * 64, b = blockIdx.z;
  const int t = threadIdx.x, c = t & 15, r = t >> 4;
  const float4* u4 = (const float4*)(u + (size_t)b * 8192 * 256);
  float* Tf = (float*)T;
#pragma unroll
  for (int p = 0; p < 4; ++p) {
    int li = r + 16 * p;
    float4 v = u4[(size_t)(l0 + li) * 64 + (d0 >> 2) + c];
    int lc = li >> 2, lk = li & 3;
#pragma unroll
    for (int k = 0; k < 4; ++k) {
      int dr = 4 * c + k;                       // tile row = d
      Tf[(dr * 16 + (lc ^ (dr & 15))) * 4 + lk] = ((const float*)&v)[k];
    }
  }
  __syncthreads();
#pragma unroll
  for (int p = 0; p < 4; ++p) {
    int dr = r + 16 * p;
    float4 w = T[dr * 16 + (c ^ (dr & 15))];
    *(float4*)&xT[(size_t)(b * 256 + d0 + dr) * 8192 + l0 + 4 * c] = w;
  }
}

// yT (2048,8192) -> out (8,8192,256), same structure with l/d roles swapped.
__global__ void transpose_out(const float* __restrict__ yT, float* __restrict__ out) {
  __shared__ float4 T[64 * 16];
  const int l0 = blockIdx.x * 64, d0 = blockIdx.y * 64, b = blockIdx.z;
  const int t = threadIdx.x, c = t & 15, r = t >> 4;
  float* Tf = (float*)T;
#pragma unroll
  for (int p = 0; p < 4; ++p) {
    int di = r + 16 * p;
    float4 v = *(const float4*)&yT[(size_t)(b * 256 + d0 + di) * 8192 + l0 + 4 * c];
    int dc = di >> 2, dk = di & 3;
#pragma unroll
    for (int k = 0; k < 4; ++k) {
      int lr = 4 * c + k;                       // tile row = l
      Tf[(lr * 16 + (dc ^ (lr & 15))) * 4 + dk] = ((const float*)&v)[k];
    }
  }
  __syncthreads();
#pragma unroll
  for (int p = 0; p < 4; ++p) {
    int lr = r + 16 * p;
    float4 w = T[lr * 16 + (c ^ (lr & 15))];
    *(float4*)&out[(size_t)(b * 8192 + l0 + lr) * 256 + d0 + 4 * c] = w;
  }
}

// One row per block: z = x0 + i*x1 (4096 each, zero-pad to 8192), fwd FFT,
// per filter half j: W = Z*Hhat_j, inv FFT, gather shifted taps:
// y[l] = Re w0[l+4095] + Im w0[l-1] + Re w1[l-1] + Im w1[l-4097]
__global__ __launch_bounds__(TPB, 4) void conv_main(const float* __restrict__ xT,
                                                    const float2* __restrict__ Hbuf,
                                                    float* __restrict__ yT) {
  __shared__ __align__(16) float2 A[LDS_F2];
  const int tid = threadIdx.x;
  const int r = blockIdx.x;
  const int f = r >> 3;                          // row_filter = r // 8
  const float4* x4 = (const float4*)(xT + (size_t)r * 8192);
#pragma unroll
  for (int m = 0; m < 2; ++m) {
    int g = tid + TPB * m;                       // 0..1023
    float4 a = x4[g];                            // x0[4g..4g+3]
    float4 b = x4[g + 1024];                     // x1[4g..4g+3]
    int p = 4 * g;
    *(float4*)&A[PX(p)]     = make_float4(a.x, b.x, a.y, b.y);
    *(float4*)&A[PX(p + 2)] = make_float4(a.z, b.z, a.w, b.w);
    int z = p + 4096;
    *(float4*)&A[PX(z)]     = make_float4(0.f, 0.f, 0.f, 0.f);
    *(float4*)&A[PX(z + 2)] = make_float4(0.f, 0.f, 0.f, 0.f);
  }
  fft_fwd(A, tid);
  __syncthreads();
  float Zr[16], Zi[16];                          // final fwd radix-2 in regs
#pragma unroll
  for (int m = 0; m < 8; ++m) {
    int p = 2 * (tid + TPB * m);
    float4 za = *(const float4*)&A[PX(p)];
    Zr[2*m]   = za.x + za.z;  Zi[2*m]   = za.y + za.w;
    Zr[2*m+1] = za.x - za.z;  Zi[2*m+1] = za.y - za.w;
  }
  const float2* H0 = Hbuf + (size_t)(2 * f) * 8192;
  const float2* H1 = H0 + 8192;
  float p0[16];
  // ---------- half 0: W = Z*H0, undo radix-2, inverse ----------
#pragma unroll
  for (int m = 0; m < 8; ++m) {
    int p = 2 * (tid + TPB * m);
    float4 hv = *(const float4*)&H0[p];
    float w0r = Zr[2*m]*hv.x - Zi[2*m]*hv.y,  w0i = Zr[2*m]*hv.y + Zi[2*m]*hv.x;
    float w1r = Zr[2*m+1]*hv.z - Zi[2*m+1]*hv.w, w1i = Zr[2*m+1]*hv.w + Zi[2*m+1]*hv.z;
    *(float4*)&A[PX(p)] = make_float4(w0r + w1r, w0i + w1i, w0r - w1r, w0i - w1i);
  }
  fft_inv(A, tid);
  __syncthreads();
#pragma unroll
  for (int m = 0; m < 16; ++m) {
    int l = tid + TPB * m;
    float acc = 0.f;
    if (l <= 4096) acc += A[PX(l + 4095)].x;     // (x0*h0)[l+4095]
    if (l >= 1)    acc += A[PX(l - 1)].y;        // (x1*h0)[l-1]
    p0[m] = acc;
  }
  __syncthreads();                               // p0 reads done before overwrite
  // ---------- half 1 ----------
#pragma unroll
  for (int m = 0; m < 8; ++m) {
    int p = 2 * (tid + TPB * m);
    float4 hv = *(const float4*)&H1[p];
    float w0r = Zr[2*m]*hv.x - Zi[2*m]*hv.y,  w0i = Zr[2*m]*hv.y + Zi[2*m]*hv.x;
    float w1r = Zr[2*m+1]*hv.z - Zi[2*m+1]*hv.w, w1i = Zr[2*m+1]*hv.w + Zi[2*m+1]*hv.z;
    *(float4*)&A[PX(p)] = make_float4(w0r + w1r, w0i + w1i, w0r - w1r, w0i - w1i);
  }
  fft_inv(A, tid);
  __syncthreads();
  float* yrow = yT + (size_t)r * 8192;
#pragma unroll
  for (int m = 0; m < 16; ++m) {
    int l = tid + TPB * m;
    float acc = p0[m];
    if (l >= 1)    acc += A[PX(l - 1)].x;        // (x0*h1)[l-1]
    if (l >= 4097) acc += A[PX(l - 4097)].y;     // (x1*h1)[l-4097]
    yrow[l] = acc;
  }
}

extern "C" void kernel_launch(void* const* d_in, const int* in_sizes, int n_in,
                              void* d_out, int out_size, void* d_ws, size_t ws_size,
                              hipStream_t stream) {
  (void)in_sizes; (void)n_in; (void)out_size; (void)ws_size;
  const float* u = (const float*)d_in[0];   // (8, 8192, 256) f32
  const float* h = (const float*)d_in[1];   // (256, 8192) f32
  float* out = (float*)d_out;               // (8, 8192, 256) f32
  // workspace: [xT/yT: 2048*8192 f32 = 64 MB][Hhat: 512*8192 float2 = 32 MB]
  float* xT = (float*)d_ws;
  float2* Hbuf = (float2*)((char*)d_ws + (size_t)2048 * 8192 * 4);

  h_fft<<<512, TPB, 0, stream>>>(h, Hbuf);
  transpose_in<<<dim3(128, 4, 8), 256, 0, stream>>>(u, xT);
  conv_main<<<2048, TPB, 0, stream>>>(xT, Hbuf, xT);   // yT aliases xT (row-local)
  transpose_out<<<dim3(128, 4, 8), 256, 0, stream>>>(xT, out);
}

// Round 3
// 470.449 us; speedup vs baseline: 1.0990x; 1.0990x over previous
//
#include <hip/hip_runtime.h>

#define TPB 512

// Pin exactly 4 waves/EU (LDS already caps at 2 blocks/CU = 4 waves/EU):
// gives the allocator the full 128-VGPR budget instead of spilling to chase
// 8 waves/EU that LDS makes impossible.
#define OCC __attribute__((amdgpu_waves_per_eu(4, 4)))

// Padded LDS addressing (float2 units): physical = p + 2*(p>>5).
// +2 float2 per 32 keeps 16B alignment for b128 (even p stays even), and all
// radix-4 stage strides (2048,512,128,32,8,2) land at <=4 lanes/bank-pair.
// For all stage offsets used below, (base0%32 + off%32) < 32, so
// PX(base0+off) == PX(base0) + PX(off): offsets fold to ds immediates.
__device__ constexpr int PX(int p) { return p + 2 * (p >> 5); }

// One radix-4 stage, compile-time S. Fwd = DIF (natural->digit-reversed),
// Inv = DIT (digit-reversed->natural), conj twiddles, unscaled (growth folded
// into Hhat). For S<=512, np = tid&(S-1) is identical for all 4 butterflies
// -> one sincos per stage. For S=2048, twiddle advances by exp(-/+ i*pi/8).
template<int S, bool INV>
__device__ __forceinline__ void fft_stage(float2* __restrict__ A, int tid) {
  constexpr int LG = (S==2048)?11:(S==512)?9:(S==128)?7:(S==32)?5:(S==8)?3:1;
  constexpr int MOFF = (S==2048) ? 512 : 2048;   // butterfly-index step per m
  const int np = tid & (S - 1);
  const int base0 = ((tid >> LG) << (LG + 2)) | np;
  float2* P = A + PX(base0);
  const float tws = (INV ? 1.5707963267948966f : -1.5707963267948966f) / (float)S;
  float c1, s1;
  __sincosf(tws * (float)np, &s1, &c1);
  float c2 = c1*c1 - s1*s1, s2 = 2.f*c1*s1;
  float c3 = c1*c2 - s1*s2, s3 = c1*s2 + s1*c2;
  __syncthreads();
#pragma unroll
  for (int m = 0; m < 4; ++m) {
    if (S == 2048 && m) {   // advance twiddle: w *= exp(-/+ i*pi/8)
      constexpr float WC = 0.92387953251128674f;
      const float WS = INV ? 0.38268343236508978f : -0.38268343236508978f;
      float t = c1*WC - s1*WS; s1 = c1*WS + s1*WC; c1 = t;
      c2 = c1*c1 - s1*s1; s2 = 2.f*c1*s1;
      c3 = c1*c2 - s1*s2; s3 = c1*s2 + s1*c2;
    }
    const int o0 = PX(MOFF*m);
    const int o1 = PX(MOFF*m + S);
    const int o2 = PX(MOFF*m + 2*S);
    const int o3 = PX(MOFF*m + 3*S);
    if (!INV) {
      float2 a = P[o0], b = P[o1], c = P[o2], d = P[o3];
      float t0r = a.x + c.x, t0i = a.y + c.y;
      float t1r = a.x - c.x, t1i = a.y - c.y;
      float t2r = b.x + d.x, t2i = b.y + d.y;
      float t3r = b.x - d.x, t3i = b.y - d.y;
      float u0r = t0r + t2r, u0i = t0i + t2i;
      float u2r = t0r - t2r, u2i = t0i - t2i;
      float u1r = t1r + t3i, u1i = t1i - t3r;   // (a-c) - i(b-d)
      float u3r = t1r - t3i, u3i = t1i + t3r;   // (a-c) + i(b-d)
      P[o0] = make_float2(u0r, u0i);
      P[o1] = make_float2(u1r*c1 - u1i*s1, u1r*s1 + u1i*c1);
      P[o2] = make_float2(u2r*c2 - u2i*s2, u2r*s2 + u2i*c2);
      P[o3] = make_float2(u3r*c3 - u3i*s3, u3r*s3 + u3i*c3);
    } else {
      float2 v0 = P[o0], u1 = P[o1], u2 = P[o2], u3 = P[o3];
      float v1r = u1.x*c1 - u1.y*s1, v1i = u1.x*s1 + u1.y*c1;
      float v2r = u2.x*c2 - u2.y*s2, v2i = u2.x*s2 + u2.y*c2;
      float v3r = u3.x*c3 - u3.y*s3, v3i = u3.x*s3 + u3.y*c3;
      P[o0] = make_float2(v0.x + v1r + v2r + v3r, v0.y + v1i + v2i + v3i);
      P[o1] = make_float2(v0.x - v1i - v2r + v3i, v0.y + v1r - v2i - v3r);
      P[o2] = make_float2(v0.x - v1r + v2r - v3r, v0.y - v1i + v2i - v3i);
      P[o3] = make_float2(v0.x + v1i - v2r - v3i, v0.y - v1r - v2i + v3r);
    }
  }
}

__device__ __forceinline__ void fft_fwd(float2* A, int tid) {
  fft_stage<2048,false>(A,tid); fft_stage<512,false>(A,tid);
  fft_stage<128,false>(A,tid);  fft_stage<32,false>(A,tid);
  fft_stage<8,false>(A,tid);    fft_stage<2,false>(A,tid);
}
__device__ __forceinline__ void fft_inv(float2* A, int tid) {
  fft_stage<2,true>(A,tid);   fft_stage<8,true>(A,tid);
  fft_stage<32,true>(A,tid);  fft_stage<128,true>(A,tid);
  fft_stage<512,true>(A,tid); fft_stage<2048,true>(A,tid);
}

#define LDS_F2 8704   // PX(8191)=8701 -> 8704 float2 = 69,632 B (2 blocks/CU)

// Hhat[2f+half][p] = DIF-scrambled FFT8192(h[f, half*4096:+4096] zero-pad)/8192
__global__ __launch_bounds__(TPB) OCC void h_fft(const float* __restrict__ h,
                                                 float2* __restrict__ Hbuf) {
  __shared__ __align__(16) float2 A[LDS_F2];
  const int tid = threadIdx.x;
  const int q = blockIdx.x;                     // q = 2*f + half
  const float4* h4 = (const float4*)(h + (size_t)(q >> 1) * 8192 + (size_t)(q & 1) * 4096);
#pragma unroll
  for (int m = 0; m < 2; ++m) {
    int g = tid + TPB * m;                      // 0..1023
    float4 a = h4[g];
    int p = 4 * g;
    *(float4*)&A[PX(p)]     = make_float4(a.x, 0.f, a.y, 0.f);
    *(float4*)&A[PX(p + 2)] = make_float4(a.z, 0.f, a.w, 0.f);
    int z = p + 4096;
    *(float4*)&A[PX(z)]     = make_float4(0.f, 0.f, 0.f, 0.f);
    *(float4*)&A[PX(z + 2)] = make_float4(0.f, 0.f, 0.f, 0.f);
  }
  fft_fwd(A, tid);
  __syncthreads();
  float2* orow = Hbuf + (size_t)q * 8192;
  const float sc = 1.f / 8192.f;
#pragma unroll
  for (int m = 0; m < 8; ++m) {
    int p = 2 * (tid + TPB * m);
    float4 za = *(const float4*)&A[PX(p)];      // final radix-2 in regs
    *(float4*)&orow[p] = make_float4((za.x + za.z) * sc, (za.y + za.w) * sc,
                                     (za.x - za.z) * sc, (za.y - za.w) * sc);
  }
}

// u (8,8192,256) -> xT (2048,8192). float4 both sides via XOR-swizzled tile.
__global__ void transpose_in(const float* __restrict__ u, float* __restrict__ xT) {
  __shared__ float4 T[64 * 16];
  const int l0 = blockIdx.x * 64, d0 = blockIdx.y * 64, b = blockIdx.z;
  const int t = threadIdx.x, c = t & 15, r = t >> 4;
  const float4* u4 = (const float4*)(u + (size_t)b * 8192 * 256);
  float* Tf = (float*)T;
#pragma unroll
  for (int p = 0; p < 4; ++p) {
    int li = r + 16 * p;
    float4 v = u4[(size_t)(l0 + li) * 64 + (d0 >> 2) + c];
    int lc = li >> 2, lk = li & 3;
#pragma unroll
    for (int k = 0; k < 4; ++k) {
      int dr = 4 * c + k;                       // tile row = d
      Tf[(dr * 16 + (lc ^ (dr & 15))) * 4 + lk] = ((const float*)&v)[k];
    }
  }
  __syncthreads();
#pragma unroll
  for (int p = 0; p < 4; ++p) {
    int dr = r + 16 * p;
    float4 w = T[dr * 16 + (c ^ (dr & 15))];
    *(float4*)&xT[(size_t)(b * 256 + d0 + dr) * 8192 + l0 + 4 * c] = w;
  }
}

// yT (2048,8192) -> out (8,8192,256), same structure with l/d roles swapped.
__global__ void transpose_out(const float* __restrict__ yT, float* __restrict__ out) {
  __shared__ float4 T[64 * 16];
  const int l0 = blockIdx.x * 64, d0 = blockIdx.y * 64, b = blockIdx.z;
  const int t = threadIdx.x, c = t & 15, r = t >> 4;
  float* Tf = (float*)T;
#pragma unroll
  for (int p = 0; p < 4; ++p) {
    int di = r + 16 * p;
    float4 v = *(const float4*)&yT[(size_t)(b * 256 + d0 + di) * 8192 + l0 + 4 * c];
    int dc = di >> 2, dk = di & 3;
#pragma unroll
    for (int k = 0; k < 4; ++k) {
      int lr = 4 * c + k;                       // tile row = l
      Tf[(lr * 16 + (dc ^ (lr & 15))) * 4 + dk] = ((const float*)&v)[k];
    }
  }
  __syncthreads();
#pragma unroll
  for (int p = 0; p < 4; ++p) {
    int lr = r + 16 * p;
    float4 w = T[lr * 16 + (c ^ (lr & 15))];
    *(float4*)&out[(size_t)(b * 8192 + l0 + lr) * 256 + d0 + 4 * c] = w;
  }
}

#define REP16(M) M(0) M(1) M(2) M(3) M(4) M(5) M(6) M(7) \
                 M(8) M(9) M(10) M(11) M(12) M(13) M(14) M(15)

// One row per block: z = x0 + i*x1 (4096 each, zero-pad to 8192), fwd FFT,
// per filter half j: W = Z*Hhat_j, inv FFT, gather shifted taps:
// y[l] = Re w0[l+4095] + Im w0[l-1] + Re w1[l-1] + Im w1[l-4097]
__global__ __launch_bounds__(TPB) OCC void conv_main(const float* __restrict__ xT,
                                                     const float2* __restrict__ Hbuf,
                                                     float* yT) {
  __shared__ __align__(16) float2 A[LDS_F2];
  const int tid = threadIdx.x;
  // XCD swizzle: empirically block i -> XCD (i%8). Give each XCD consecutive
  // blocks that share one filter f so Hhat rows are L2-resident (8x reuse).
  const int i = blockIdx.x;
  const int f = ((i >> 6) << 3) | (i & 7);       // filter 0..255
  const int r = (f << 3) | ((i >> 3) & 7);       // row 0..2047 (bijective)
  const float4* x4 = (const float4*)(xT + (size_t)r * 8192);
#pragma unroll
  for (int m = 0; m < 2; ++m) {
    int g = tid + TPB * m;                       // 0..1023
    float4 a = x4[g];                            // x0[4g..4g+3]
    float4 b = x4[g + 1024];                     // x1[4g..4g+3]
    int p = 4 * g;
    *(float4*)&A[PX(p)]     = make_float4(a.x, b.x, a.y, b.y);
    *(float4*)&A[PX(p + 2)] = make_float4(a.z, b.z, a.w, b.w);
    int z = p + 4096;
    *(float4*)&A[PX(z)]     = make_float4(0.f, 0.f, 0.f, 0.f);
    *(float4*)&A[PX(z + 2)] = make_float4(0.f, 0.f, 0.f, 0.f);
  }
  fft_fwd(A, tid);
  __syncthreads();
  // Final fwd radix-2 into NAMED scalars (guaranteed register promotion).
#define ZDECL(k) float zr##k, zi##k;
  REP16(ZDECL)
#define EXTQ(m, A0, A1) { \
    float4 za = *(const float4*)&A[PX(2 * (tid + TPB * m))]; \
    zr##A0 = za.x + za.z;  zi##A0 = za.y + za.w; \
    zr##A1 = za.x - za.z;  zi##A1 = za.y - za.w; }
  EXTQ(0,0,1)  EXTQ(1,2,3)  EXTQ(2,4,5)  EXTQ(3,6,7)
  EXTQ(4,8,9)  EXTQ(5,10,11) EXTQ(6,12,13) EXTQ(7,14,15)
  const float2* H0 = Hbuf + (size_t)(2 * f) * 8192;
  const float2* H1 = H0 + 8192;
#define MULQ(m, A0, A1, H) { \
    int p = 2 * (tid + TPB * m); \
    float4 hv = *(const float4*)&H[p]; \
    float w0r = zr##A0*hv.x - zi##A0*hv.y, w0i = zr##A0*hv.y + zi##A0*hv.x; \
    float w1r = zr##A1*hv.z - zi##A1*hv.w, w1i = zr##A1*hv.w + zi##A1*hv.z; \
    *(float4*)&A[PX(p)] = make_float4(w0r + w1r, w0i + w1i, w0r - w1r, w0i - w1i); }
  // ---------- half 0: W = Z*H0, undo radix-2, inverse ----------
  MULQ(0,0,1,H0)  MULQ(1,2,3,H0)  MULQ(2,4,5,H0)  MULQ(3,6,7,H0)
  MULQ(4,8,9,H0)  MULQ(5,10,11,H0) MULQ(6,12,13,H0) MULQ(7,14,15,H0)
  fft_inv(A, tid);
  __syncthreads();
#define PDECL(k) float p0_##k;
  REP16(PDECL)
#define G0Q(m) { \
    int l = tid + TPB * m; \
    float acc = 0.f; \
    if (l <= 4096) acc += A[PX(l + 4095)].x; \
    if (l >= 1)    acc += A[PX(l - 1)].y; \
    p0_##m = acc; }
  REP16(G0Q)
  __syncthreads();                               // p0 reads done before overwrite
  // ---------- half 1 ----------
  MULQ(0,0,1,H1)  MULQ(1,2,3,H1)  MULQ(2,4,5,H1)  MULQ(3,6,7,H1)
  MULQ(4,8,9,H1)  MULQ(5,10,11,H1) MULQ(6,12,13,H1) MULQ(7,14,15,H1)
  fft_inv(A, tid);
  __syncthreads();
  float* yrow = yT + (size_t)r * 8192;
#define G1Q(m) { \
    int l = tid + TPB * m; \
    float acc = p0_##m; \
    if (l >= 1)    acc += A[PX(l - 1)].x; \
    if (l >= 4097) acc += A[PX(l - 4097)].y; \
    yrow[l] = acc; }
  REP16(G1Q)
}

extern "C" void kernel_launch(void* const* d_in, const int* in_sizes, int n_in,
                              void* d_out, int out_size, void* d_ws, size_t ws_size,
                              hipStream_t stream) {
  (void)in_sizes; (void)n_in; (void)out_size; (void)ws_size;
  const float* u = (const float*)d_in[0];   // (8, 8192, 256) f32
  const float* h = (const float*)d_in[1];   // (256, 8192) f32
  float* out = (float*)d_out;               // (8, 8192, 256) f32
  // workspace: [xT/yT: 2048*8192 f32 = 64 MB][Hhat: 512*8192 float2 = 32 MB]
  float* xT = (float*)d_ws;
  float2* Hbuf = (float2*)((char*)d_ws + (size_t)2048 * 8192 * 4);

  h_fft<<<512, TPB, 0, stream>>>(h, Hbuf);
  transpose_in<<<dim3(128, 4, 8), 256, 0, stream>>>(u, xT);
  conv_main<<<2048, TPB, 0, stream>>>(xT, Hbuf, xT);   // yT aliases xT (row-local)
  transpose_out<<<dim3(128, 4, 8), 256, 0, stream>>>(xT, out);
}

// Round 4
// 275.978 us; speedup vs baseline: 1.8734x; 1.7047x over previous
//
#include <hip/hip_runtime.h>

#define TPB 1024   // one 16384-pt FFT per block, 4 butterflies/thread/stage

// Padded LDS addressing (float2 units): physical = p + 2*(p>>5).
// Keeps 16B alignment (even p stays even); for every stage offset used below
// (base%32 + off%32) < 32, so PX(base+off) == PX(base)+PX(off) and offsets
// fold into ds immediates / per-m bases.
__device__ constexpr int PX(int p) { return p + 2 * (p >> 5); }

#define LDS_F2 17408   // PX(16383)=17405 -> 139,264 B (1 block/CU)
#define LDS_BYTES (LDS_F2 * 8)

// One radix-4 stage of a 16384-pt FFT, compile-time quarter-stride S.
// Fwd = DIF (natural -> digit-reversed), Inv = DIT (digit-reversed -> natural),
// conj twiddles, unscaled (4^7 = 16384 growth folded into Hhat).
// For S<=1024, np = tid&(S-1) is identical for all 4 butterflies -> one
// sincos per stage. For S=4096, twiddle advances by exp(-/+ i*pi/8) per m.
// S==1: all twiddles are 1 (folded at compile time).
template<int S, bool INV>
__device__ __forceinline__ void fft_stage(float2* __restrict__ A, int tid) {
  constexpr int LG = (S==4096)?12:(S==1024)?10:(S==256)?8:(S==64)?6:(S==16)?4:(S==4)?2:0;
  const int np = tid & (S - 1);
  const int base0 = ((tid >> LG) << (LG + 2)) | np;
  float2* P = A + PX(base0);
  const float tws = (INV ? 1.5707963267948966f : -1.5707963267948966f) / (float)S;
  float c1, s1;
  if (S == 1) { c1 = 1.f; s1 = 0.f; } else { __sincosf(tws * (float)np, &s1, &c1); }
  float c2 = c1*c1 - s1*s1, s2 = 2.f*c1*s1;
  float c3 = c1*c2 - s1*s2, s3 = c1*s2 + s1*c2;
  __syncthreads();
#pragma unroll
  for (int m = 0; m < 4; ++m) {
    if (S == 4096 && m) {   // np step 1024 -> angle step -/+ pi/8
      constexpr float WC = 0.92387953251128674f;
      const float WS = INV ? 0.38268343236508978f : -0.38268343236508978f;
      float t = c1*WC - s1*WS; s1 = c1*WS + s1*WC; c1 = t;
      c2 = c1*c1 - s1*s1; s2 = 2.f*c1*s1;
      c3 = c1*c2 - s1*s2; s3 = c1*s2 + s1*c2;
    }
    const int mo = (S == 4096) ? 1024 * m : 4096 * m;   // butterfly base step
    const int o0 = PX(mo);
    const int o1 = PX(mo + S);
    const int o2 = PX(mo + 2*S);
    const int o3 = PX(mo + 3*S);
    if (!INV) {
      float2 a = P[o0], b = P[o1], c = P[o2], d = P[o3];
      float t0r = a.x + c.x, t0i = a.y + c.y;
      float t1r = a.x - c.x, t1i = a.y - c.y;
      float t2r = b.x + d.x, t2i = b.y + d.y;
      float t3r = b.x - d.x, t3i = b.y - d.y;
      float u0r = t0r + t2r, u0i = t0i + t2i;
      float u2r = t0r - t2r, u2i = t0i - t2i;
      float u1r = t1r + t3i, u1i = t1i - t3r;   // (a-c) - i(b-d)
      float u3r = t1r - t3i, u3i = t1i + t3r;   // (a-c) + i(b-d)
      P[o0] = make_float2(u0r, u0i);
      P[o1] = make_float2(u1r*c1 - u1i*s1, u1r*s1 + u1i*c1);
      P[o2] = make_float2(u2r*c2 - u2i*s2, u2r*s2 + u2i*c2);
      P[o3] = make_float2(u3r*c3 - u3i*s3, u3r*s3 + u3i*c3);
    } else {
      float2 v0 = P[o0], u1 = P[o1], u2 = P[o2], u3 = P[o3];
      float v1r = u1.x*c1 - u1.y*s1, v1i = u1.x*s1 + u1.y*c1;
      float v2r = u2.x*c2 - u2.y*s2, v2i = u2.x*s2 + u2.y*c2;
      float v3r = u3.x*c3 - u3.y*s3, v3i = u3.x*s3 + u3.y*c3;
      P[o0] = make_float2(v0.x + v1r + v2r + v3r, v0.y + v1i + v2i + v3i);
      P[o1] = make_float2(v0.x - v1i - v2r + v3i, v0.y + v1r - v2i - v3r);
      P[o2] = make_float2(v0.x - v1r + v2r - v3r, v0.y - v1i + v2i - v3i);
      P[o3] = make_float2(v0.x + v1i - v2r - v3i, v0.y - v1r - v2i + v3r);
    }
  }
}

__device__ __forceinline__ void fft_fwd(float2* A, int tid) {
  fft_stage<4096,false>(A,tid); fft_stage<1024,false>(A,tid);
  fft_stage<256,false>(A,tid);  fft_stage<64,false>(A,tid);
  fft_stage<16,false>(A,tid);   fft_stage<4,false>(A,tid);
  fft_stage<1,false>(A,tid);
}
__device__ __forceinline__ void fft_inv(float2* A, int tid) {
  fft_stage<1,true>(A,tid);    fft_stage<4,true>(A,tid);
  fft_stage<16,true>(A,tid);   fft_stage<64,true>(A,tid);
  fft_stage<256,true>(A,tid);  fft_stage<1024,true>(A,tid);
  fft_stage<4096,true>(A,tid);
}

// Hhat[f][p] = scrambled FFT16384(h[f] zero-padded) / 16384
__global__ __launch_bounds__(TPB) void h_fft(const float* __restrict__ h,
                                             float2* __restrict__ Hbuf) {
  extern __shared__ __align__(16) float2 A[];
  const int tid = threadIdx.x;
  const int f = blockIdx.x;
  const float4* h4 = (const float4*)(h + (size_t)f * 8192);
#pragma unroll
  for (int m = 0; m < 2; ++m) {
    int g = tid + TPB * m;                      // 0..2047
    float4 a = h4[g];
    int p = 4 * g;
    *(float4*)&A[PX(p)]     = make_float4(a.x, 0.f, a.y, 0.f);
    *(float4*)&A[PX(p) + 2] = make_float4(a.z, 0.f, a.w, 0.f);
    int z = p + 8192;
    *(float4*)&A[PX(z)]     = make_float4(0.f, 0.f, 0.f, 0.f);
    *(float4*)&A[PX(z) + 2] = make_float4(0.f, 0.f, 0.f, 0.f);
  }
  fft_fwd(A, tid);
  __syncthreads();
  float2* orow = Hbuf + (size_t)f * 16384;
  const float sc = 1.f / 16384.f;
#pragma unroll
  for (int m = 0; m < 8; ++m) {
    int p = 2 * (tid + TPB * m);
    float4 za = *(const float4*)&A[PX(p)];
    *(float4*)&orow[p] = make_float4(za.x * sc, za.y * sc, za.z * sc, za.w * sc);
  }
}

// u (8,8192,256) -> xT (2048,8192). float4 both sides via XOR-swizzled tile.
__global__ void transpose_in(const float* __restrict__ u, float* __restrict__ xT) {
  __shared__ float4 T[64 * 16];
  const int l0 = blockIdx.x * 64, d0 = blockIdx.y * 64, b = blockIdx.z;
  const int t = threadIdx.x, c = t & 15, r = t >> 4;
  const float4* u4 = (const float4*)(u + (size_t)b * 8192 * 256);
  float* Tf = (float*)T;
#pragma unroll
  for (int p = 0; p < 4; ++p) {
    int li = r + 16 * p;
    float4 v = u4[(size_t)(l0 + li) * 64 + (d0 >> 2) + c];
    int lc = li >> 2, lk = li & 3;
#pragma unroll
    for (int k = 0; k < 4; ++k) {
      int dr = 4 * c + k;                       // tile row = d
      Tf[(dr * 16 + (lc ^ (dr & 15))) * 4 + lk] = ((const float*)&v)[k];
    }
  }
  __syncthreads();
#pragma unroll
  for (int p = 0; p < 4; ++p) {
    int dr = r + 16 * p;
    float4 w = T[dr * 16 + (c ^ (dr & 15))];
    *(float4*)&xT[(size_t)(b * 256 + d0 + dr) * 8192 + l0 + 4 * c] = w;
  }
}

// yT (2048,8192) -> out (8,8192,256), same structure with l/d roles swapped.
__global__ void transpose_out(const float* __restrict__ yT, float* __restrict__ out) {
  __shared__ float4 T[64 * 16];
  const int l0 = blockIdx.x * 64, d0 = blockIdx.y * 64, b = blockIdx.z;
  const int t = threadIdx.x, c = t & 15, r = t >> 4;
  float* Tf = (float*)T;
#pragma unroll
  for (int p = 0; p < 4; ++p) {
    int di = r + 16 * p;
    float4 v = *(const float4*)&yT[(size_t)(b * 256 + d0 + di) * 8192 + l0 + 4 * c];
    int dc = di >> 2, dk = di & 3;
#pragma unroll
    for (int k = 0; k < 4; ++k) {
      int lr = 4 * c + k;                       // tile row = l
      Tf[(lr * 16 + (dc ^ (lr & 15))) * 4 + dk] = ((const float*)&v)[k];
    }
  }
  __syncthreads();
#pragma unroll
  for (int p = 0; p < 4; ++p) {
    int lr = r + 16 * p;
    float4 w = T[lr * 16 + (c ^ (lr & 15))];
    *(float4*)&out[(size_t)(b * 8192 + l0 + lr) * 256 + d0 + 4 * c] = w;
  }
}

// One block per ROW PAIR (r, r+1 share filter f = r>>3):
// z = x_r + i*x_{r+1}, zero-pad to 16384, fwd FFT, W = Z*Hhat[f] (streamed
// from global), inv FFT, y_r[l] = W[l+4095].x, y_{r+1}[l] = W[l+4095].y.
// Linear conv length 16383 <= 16384: no circular aliasing, no guards.
__global__ __launch_bounds__(TPB) void conv_main(const float* __restrict__ xT,
                                                 const float2* __restrict__ Hbuf,
                                                 float* yT) {
  extern __shared__ __align__(16) float2 A[];
  const int tid = threadIdx.x;
  // XCD swizzle: block i -> XCD (i%8); the 4 pair-blocks of one filter land
  // on the same XCD consecutively -> Hhat row (128 KB) is L2-resident.
  const int i = blockIdx.x;
  const int f = ((i >> 5) << 3) | (i & 7);      // filter 0..255
  const int r = (f << 3) | (((i >> 3) & 3) << 1); // row 0..2046 (even)
  const float4* xr0 = (const float4*)(xT + (size_t)r * 8192);
  const float4* xr1 = (const float4*)(xT + (size_t)(r + 1) * 8192);
#pragma unroll
  for (int m = 0; m < 2; ++m) {
    int g = tid + TPB * m;                      // 0..2047
    float4 a = xr0[g];
    float4 b = xr1[g];
    int p = 4 * g;
    *(float4*)&A[PX(p)]     = make_float4(a.x, b.x, a.y, b.y);
    *(float4*)&A[PX(p) + 2] = make_float4(a.z, b.z, a.w, b.w);
    int z = p + 8192;
    *(float4*)&A[PX(z)]     = make_float4(0.f, 0.f, 0.f, 0.f);
    *(float4*)&A[PX(z) + 2] = make_float4(0.f, 0.f, 0.f, 0.f);
  }
  fft_fwd(A, tid);
  __syncthreads();
  // Pointwise multiply by Hhat[f] (same scrambled order), streamed from L2.
  const float2* Hrow = Hbuf + (size_t)f * 16384;
#pragma unroll
  for (int m = 0; m < 8; ++m) {
    int p = 2 * (tid + TPB * m);
    float4 za = *(const float4*)&A[PX(p)];
    float4 hv = *(const float4*)&Hrow[p];
    *(float4*)&A[PX(p)] = make_float4(za.x*hv.x - za.y*hv.y, za.x*hv.y + za.y*hv.x,
                                      za.z*hv.z - za.w*hv.w, za.z*hv.w + za.w*hv.z);
  }
  fft_inv(A, tid);
  __syncthreads();
  float* y0 = yT + (size_t)r * 8192;
  float* y1 = yT + (size_t)(r + 1) * 8192;
#pragma unroll
  for (int m = 0; m < 8; ++m) {
    int l = tid + TPB * m;                      // 0..8191
    float2 w = A[PX(l + 4095)];
    y0[l] = w.x;
    y1[l] = w.y;
  }
}

extern "C" void kernel_launch(void* const* d_in, const int* in_sizes, int n_in,
                              void* d_out, int out_size, void* d_ws, size_t ws_size,
                              hipStream_t stream) {
  (void)in_sizes; (void)n_in; (void)out_size; (void)ws_size;
  const float* u = (const float*)d_in[0];   // (8, 8192, 256) f32
  const float* h = (const float*)d_in[1];   // (256, 8192) f32
  float* out = (float*)d_out;               // (8, 8192, 256) f32
  // workspace: [xT/yT: 2048*8192 f32 = 64 MB][Hhat: 256*16384 float2 = 32 MB]
  float* xT = (float*)d_ws;
  float2* Hbuf = (float2*)((char*)d_ws + (size_t)2048 * 8192 * 4);

  // Opt in to >64 KB dynamic LDS (idempotent; non-stream call, capture-safe).
  static_assert(LDS_BYTES == 139264, "lds");
  (void)hipFuncSetAttribute((const void*)h_fft,
      hipFuncAttributeMaxDynamicSharedMemorySize, LDS_BYTES);
  (void)hipFuncSetAttribute((const void*)conv_main,
      hipFuncAttributeMaxDynamicSharedMemorySize, LDS_BYTES);

  h_fft<<<256, TPB, LDS_BYTES, stream>>>(h, Hbuf);
  transpose_in<<<dim3(128, 4, 8), 256, 0, stream>>>(u, xT);
  conv_main<<<1024, TPB, LDS_BYTES, stream>>>(xT, Hbuf, xT);  // yT aliases xT
  transpose_out<<<dim3(128, 4, 8), 256, 0, stream>>>(xT, out);
}